// Round 10
// baseline (281.954 us; speedup 1.0000x reference)
//
#include <hip/hip_runtime.h>
#include <hip/hip_bf16.h>

typedef unsigned short ushort_t;
typedef __attribute__((ext_vector_type(8))) short short8;   // 8 x bf16 (4 VGPRs)
typedef __attribute__((ext_vector_type(4))) float floatx4;  // MFMA acc

#define BATCH 4
#define SEQ   2048
#define CH    1024
#define NHEAD 16
#define HSZ   64
#define MROWS (BATCH * SEQ)  // 8192

// async global->LDS, 16B per lane; LDS dest = wave-uniform base + lane*16
#define GLD16(gptr, lptr) \
    __builtin_amdgcn_global_load_lds((const __attribute__((address_space(1))) unsigned int*)(gptr), \
                                     (__attribute__((address_space(3))) unsigned int*)(lptr), 16, 0, 0)

__device__ inline ushort_t f2b(float f) {
    __hip_bfloat16 h = __float2bfloat16(f);
    return *(ushort_t*)&h;
}
__device__ inline float b2f(ushort_t u) {
    return __bfloat162float(*(__hip_bfloat16*)&u);
}

// -------- fused dtype-detect + bias convert --------------------------------------
// Wave 0: flag = 1 if x is bf16 (even-ushort exponents cluster in [100,140]),
// 0 if f32 (uniform mantissa bits). Then all 256 threads convert 4x1024 biases.
__global__ __launch_bounds__(256) void detect_and_bias(const ushort_t* __restrict__ x,
                                                       int* __restrict__ flag,
                                                       const void* b0, const void* b1,
                                                       const void* b2, const void* b3,
                                                       ushort_t* __restrict__ out) {
    __shared__ int sflag;
    if (threadIdx.x < 64) {
        int cnt = 0;
        #pragma unroll
        for (int i = 0; i < 8; i++) {
            const int e = (x[2 * (threadIdx.x * 8 + i)] >> 7) & 0xFF;
            const unsigned long long m = __ballot(e >= 100 && e <= 140);
            cnt += (int)__popcll(m);
        }
        if (threadIdx.x == 0) { sflag = (cnt >= 400) ? 1 : 0; *flag = sflag; }
    }
    __syncthreads();
    const int am = sflag;
    for (int i = threadIdx.x; i < 4096; i += 256) {
        const int m = i >> 10, idx = i & 1023;
        const void* in = (m == 0) ? b0 : (m == 1) ? b1 : (m == 2) ? b2 : b3;
        out[i] = am ? ((const ushort_t*)in)[idx] : f2b(((const float*)in)[idx]);
    }
}

// -------- 4x weight transpose+convert: in[k][n] -> out bf16 [n][k] ---------------
__global__ __launch_bounds__(256) void convert_wt4(const void* w0, const void* w1,
                                                   const void* w2, const void* w3,
                                                   ushort_t* o0, ushort_t* o1,
                                                   ushort_t* o2, ushort_t* o3,
                                                   const int* __restrict__ flag) {
    __shared__ ushort_t tile[32][33];
    const void* in = (blockIdx.z == 0) ? w0 : (blockIdx.z == 1) ? w1 : (blockIdx.z == 2) ? w2 : w3;
    ushort_t*  out = (blockIdx.z == 0) ? o0 : (blockIdx.z == 1) ? o1 : (blockIdx.z == 2) ? o2 : o3;
    const int am = *flag;
    const int bx = blockIdx.x * 32, by = blockIdx.y * 32;
    const int tx = threadIdx.x & 31, ty = threadIdx.x >> 5;
    #pragma unroll
    for (int r = ty; r < 32; r += 8) {
        const size_t idx = (size_t)(by + r) * CH + bx + tx;
        tile[r][tx] = am ? ((const ushort_t*)in)[idx] : f2b(((const float*)in)[idx]);
    }
    __syncthreads();
    #pragma unroll
    for (int r = ty; r < 32; r += 8)
        out[(size_t)(bx + r) * CH + by + tx] = tile[tx][r];
}

// -------- x convert: flat fp32/bf16 -> bf16, 8 elems/thread ----------------------
__global__ __launch_bounds__(256) void convert_x(const void* __restrict__ in,
                                                 ushort_t* __restrict__ out,
                                                 const int* __restrict__ flag) {
    const int i = (blockIdx.x * 256 + threadIdx.x) * 8;
    if (*flag) {
        *(float4*)&out[i] = *(const float4*)&((const ushort_t*)in)[i];
    } else {
        const float* p = (const float*)in + i;
        float4 f0 = *(const float4*)p;
        float4 f1 = *(const float4*)(p + 4);
        ushort_t t[8] = {f2b(f0.x), f2b(f0.y), f2b(f0.z), f2b(f0.w),
                         f2b(f1.x), f2b(f1.y), f2b(f1.z), f2b(f1.w)};
        *(float4*)&out[i] = *(const float4*)t;
    }
}

// -------- shared MFMA K-loop. SWAP=1: acc = Out^T fragments (lane holds row =
// lane15, 4 consecutive cols = quad*4+r -> packed epilogue stores). SWAP=0:
// classic layout (lane holds col = lane15, 4 consecutive rows). A/B frags are
// physically identical LDS reads; only the operand order differs. -------------
template <int SWAP>
__device__ __forceinline__ void mfma_kloop(const ushort_t* __restrict__ A,
                                           const ushort_t* __restrict__ Bt,
                                           int K, int row0, int col0,
                                           ushort_t* As, ushort_t* Bs,
                                           floatx4 acc[4][4],
                                           int lane, int wave) {
    const int lane15 = lane & 15, quad = lane >> 4;
    const int wr = (wave >> 1) * 64, wc = (wave & 1) * 64;
    for (int k0 = 0; k0 < K; k0 += 32) {
        #pragma unroll
        for (int l = wave; l < 8; l += 4) {
            GLD16(A  + (size_t)(row0 + l * 16 + (lane >> 2)) * K + k0 + (lane & 3) * 8, &As[l * 512]);
            GLD16(Bt + (size_t)(col0 + l * 16 + (lane >> 2)) * K + k0 + (lane & 3) * 8, &Bs[l * 512]);
        }
        __syncthreads();
        short8 af[4], bfr[4];
        #pragma unroll
        for (int i = 0; i < 4; i++)
            af[i] = *(const short8*)&As[(wr + i * 16 + lane15) * 32 + quad * 8];
        #pragma unroll
        for (int j = 0; j < 4; j++)
            bfr[j] = *(const short8*)&Bs[(wc + j * 16 + lane15) * 32 + quad * 8];
        #pragma unroll
        for (int i = 0; i < 4; i++)
            #pragma unroll
            for (int j = 0; j < 4; j++) {
                if (SWAP)
                    acc[i][j] = __builtin_amdgcn_mfma_f32_16x16x32_bf16(bfr[j], af[i], acc[i][j], 0, 0, 0);
                else
                    acc[i][j] = __builtin_amdgcn_mfma_f32_16x16x32_bf16(af[i], bfr[j], acc[i][j], 0, 0, 0);
            }
        __syncthreads();
    }
}

// ---------------- fused QKV GEMM: [8192,1024] @ [3072,1024]^T + bias -------------
// seg 0 (Q) / 1 (K): SWAP form, packed 8B row-major stores. seg 2 (V): classic
// form, packed 8B transposed-per-head stores Vt[b][n][t].
__global__ __launch_bounds__(256) void gemm_qkv(const ushort_t* __restrict__ A,
                                                const ushort_t* __restrict__ Bt,
                                                const ushort_t* __restrict__ bias,
                                                ushort_t* __restrict__ Qb,
                                                ushort_t* __restrict__ Kb,
                                                ushort_t* __restrict__ Vt,
                                                float qscale) {
    __shared__ __align__(16) ushort_t As[128 * 32];
    __shared__ __align__(16) ushort_t Bs[128 * 32];
    const int tid = threadIdx.x;
    const int lane = tid & 63, wave = tid >> 6;
    const int lane15 = lane & 15, quad = lane >> 4;
    const int wr = (wave >> 1) * 64, wc = (wave & 1) * 64;
    const int row0 = blockIdx.x * 128, col0 = blockIdx.y * 128;
    const int seg = blockIdx.y >> 3;  // 0=Q 1=K 2=V (block-uniform)

    floatx4 acc[4][4];
    #pragma unroll
    for (int i = 0; i < 4; i++)
        #pragma unroll
        for (int j = 0; j < 4; j++) acc[i][j] = {0.f, 0.f, 0.f, 0.f};

    if (seg != 2) {
        mfma_kloop<1>(A, Bt, CH, row0, col0, As, Bs, acc, lane, wave);
        ushort_t* Out = (seg == 0) ? Qb : Kb;
        const int cadj = (seg == 0) ? 0 : 1024;
        const float sc = (seg == 0) ? qscale : 1.0f;
        #pragma unroll
        for (int j = 0; j < 4; j++) {
            const int colbase = col0 + wc + j * 16 + quad * 4;      // 4 consecutive cols
            ushort_t b4[4];
            *(uint2*)b4 = *(const uint2*)&bias[colbase];
            #pragma unroll
            for (int i = 0; i < 4; i++) {
                const int row = row0 + wr + i * 16 + lane15;
                ushort_t pk[4];
                #pragma unroll
                for (int r = 0; r < 4; r++)
                    pk[r] = f2b((acc[i][j][r] + b2f(b4[r])) * sc);
                *(uint2*)&Out[(size_t)row * CH + colbase - cadj] = *(const uint2*)pk;
            }
        }
    } else {
        mfma_kloop<0>(A, Bt, CH, row0, col0, As, Bs, acc, lane, wave);
        #pragma unroll
        for (int j = 0; j < 4; j++) {
            const int col = col0 + wc + j * 16 + lane15;
            const float bv = b2f(bias[col]);
            const int c = col - 2048;
            #pragma unroll
            for (int i = 0; i < 4; i++) {
                const int rowb = row0 + wr + i * 16 + quad * 4;     // 4 consecutive t
                ushort_t pk[4];
                #pragma unroll
                for (int r = 0; r < 4; r++) pk[r] = f2b(acc[i][j][r] + bv);
                const int bb = rowb >> 11, t = rowb & 2047;
                *(uint2*)&Vt[((size_t)bb * 1024 + c) * 2048 + t] = *(const uint2*)pk;
            }
        }
    }
}

// ---------------- output GEMM: Out = A @ Bt^T + bias (fp32 float4 / bf16 uint2) --
__global__ __launch_bounds__(256) void gemm_bt(const ushort_t* __restrict__ A,
                                               const ushort_t* __restrict__ Bt,
                                               const ushort_t* __restrict__ bias,
                                               void* __restrict__ Out,
                                               int M, int N, int K,
                                               const int* __restrict__ oflag) {
    __shared__ __align__(16) ushort_t As[128 * 32];
    __shared__ __align__(16) ushort_t Bs[128 * 32];
    const int om = *oflag;
    const int tid = threadIdx.x;
    const int lane = tid & 63, wave = tid >> 6;
    const int lane15 = lane & 15, quad = lane >> 4;
    const int wr = (wave >> 1) * 64, wc = (wave & 1) * 64;
    const int row0 = blockIdx.x * 128, col0 = blockIdx.y * 128;

    floatx4 acc[4][4];
    #pragma unroll
    for (int i = 0; i < 4; i++)
        #pragma unroll
        for (int j = 0; j < 4; j++) acc[i][j] = {0.f, 0.f, 0.f, 0.f};

    mfma_kloop<1>(A, Bt, K, row0, col0, As, Bs, acc, lane, wave);

    #pragma unroll
    for (int j = 0; j < 4; j++) {
        const int colbase = col0 + wc + j * 16 + quad * 4;          // 4 consecutive cols
        ushort_t b4[4];
        *(uint2*)b4 = *(const uint2*)&bias[colbase];
        #pragma unroll
        for (int i = 0; i < 4; i++) {
            const int row = row0 + wr + i * 16 + lane15;
            if (om) {
                ushort_t pk[4];
                #pragma unroll
                for (int r = 0; r < 4; r++) pk[r] = f2b(acc[i][j][r] + b2f(b4[r]));
                *(uint2*)&((ushort_t*)Out)[(size_t)row * N + colbase] = *(const uint2*)pk;
            } else {
                float4 v;
                v.x = acc[i][j][0] + b2f(b4[0]);
                v.y = acc[i][j][1] + b2f(b4[1]);
                v.z = acc[i][j][2] + b2f(b4[2]);
                v.w = acc[i][j][3] + b2f(b4[3]);
                *(float4*)&((float*)Out)[(size_t)row * N + colbase] = v;
            }
        }
    }
}

// ---------------- flash attention (round-6 structure: measured best) -------------
// Ps LDS round-trip decouples the S-phase from PV (overlappable across waves) —
// measured 79-81 us vs 110 us for the register-shuffle S^T form and 240 us for
// the VGPR-clamped variant. Keep: K/V dbuf, one barrier per tile, XCD-local
// (b,h) in bid&63, ones-MFMA rowsum, exp2 with scale folded into Q, swizzled
// K/V staging. DO NOT add a second __launch_bounds__ arg (round-7 spill).
__global__ __launch_bounds__(256) void attn_fwd(ushort_t* __restrict__ QY,
                                                const ushort_t* __restrict__ K,
                                                const ushort_t* __restrict__ Vt) {
    __shared__ __align__(16) ushort_t Ks[2][64 * 64];    // [buf][kv][d], swizzled
    __shared__ __align__(16) ushort_t Vs[2][64 * 64];    // [buf][d][kv], swizzled
    __shared__ __align__(16) ushort_t Ps[4 * 32 * 72];   // per-wave [q=32][kv=64], stride 72
    const int tid = threadIdx.x;
    const int lane = tid & 63, wave = tid >> 6;
    const int lane15 = lane & 15, quad = lane >> 4;
    const int sw = lane15 & 7;                            // read-side swizzle key
    const int bid = blockIdx.x;
    const int hb = bid & 63, qslot = bid >> 6;
    const int qb = 15 - qslot;
    const int h = hb & 15, b = hb >> 4;
    const int q0 = qb * 128;
    const size_t baseR = (size_t)b * SEQ * CH + h * HSZ;      // +t*CH+d (Q,K,Y)
    const size_t baseV = ((size_t)b * 1024 + h * HSZ) * SEQ;  // +d*SEQ+t (Vt)
    const int rg = lane >> 3, cg = (lane & 7) ^ rg;           // staging swizzle

    short8 qf[2][2];
    #pragma unroll
    for (int mm = 0; mm < 2; mm++) {
        const ushort_t* qp = QY + baseR + (size_t)(q0 + wave * 32 + mm * 16 + lane15) * CH + quad * 8;
        qf[mm][0] = *(const short8*)qp;
        qf[mm][1] = *(const short8*)(qp + 32);
    }
    const short8 kOnes = (short8)(short)0x3F80;  // bf16 1.0 x8

    floatx4 o[2][5];  // [mm][0..3]=O d-chunks, [4]=l (rowsum)
    #pragma unroll
    for (int mm = 0; mm < 2; mm++)
        #pragma unroll
        for (int j = 0; j < 5; j++) o[mm][j] = {0.f, 0.f, 0.f, 0.f};

    const int nkt = 2 * qb + 2;
    // preamble: stage tile 0 into buf 0
    #pragma unroll
    for (int l = wave; l < 8; l += 4) {
        GLD16(K  + baseR + (size_t)(l * 8 + rg) * CH + cg * 8, &Ks[0][l * 512]);
        GLD16(Vt + baseV + (size_t)(l * 8 + rg) * SEQ + cg * 8, &Vs[0][l * 512]);
    }

    for (int kt = 0; kt < nkt; kt++) {
        __syncthreads();  // staging of kt landed; all waves done with buf kt^1
        const int cur = kt & 1;
        if (kt + 1 < nkt) {
            const int kv1 = (kt + 1) * 64, nb = cur ^ 1;
            #pragma unroll
            for (int l = wave; l < 8; l += 4) {
                GLD16(K  + baseR + (size_t)(kv1 + l * 8 + rg) * CH + cg * 8, &Ks[nb][l * 512]);
                GLD16(Vt + baseV + (size_t)(l * 8 + rg) * SEQ + kv1 + cg * 8, &Vs[nb][l * 512]);
            }
        }
        const int kv0 = kt * 64;
        const int masked = (kt >= 2 * qb);
        #pragma unroll
        for (int mm = 0; mm < 2; mm++) {
            floatx4 s4[4];
            #pragma unroll
            for (int j = 0; j < 4; j++) {
                short8 b0 = *(const short8*)&Ks[cur][(j * 16 + lane15) * 64 + ((quad ^ sw) * 8)];
                short8 b1 = *(const short8*)&Ks[cur][(j * 16 + lane15) * 64 + (((quad + 4) ^ sw) * 8)];
                floatx4 z = {0.f, 0.f, 0.f, 0.f};
                z = __builtin_amdgcn_mfma_f32_16x16x32_bf16(qf[mm][0], b0, z, 0, 0, 0);
                z = __builtin_amdgcn_mfma_f32_16x16x32_bf16(qf[mm][1], b1, z, 0, 0, 0);
                s4[j] = z;
            }
            const int qrow_base = q0 + wave * 32 + mm * 16 + quad * 4;
            if (masked) {
                #pragma unroll
                for (int j = 0; j < 4; j++) {
                    const int col = kv0 + j * 16 + lane15;
                    #pragma unroll
                    for (int r = 0; r < 4; r++)
                        s4[j][r] = (col <= qrow_base + r) ? s4[j][r] : -1e30f;
                }
            }
            // p = 2^s  (2^-1e30 -> 0 for masked lanes)
            #pragma unroll
            for (int j = 0; j < 4; j++)
                #pragma unroll
                for (int r = 0; r < 4; r++)
                    Ps[wave * 2304 + (mm * 16 + quad * 4 + r) * 72 + j * 16 + lane15] =
                        f2b(exp2f(s4[j][r]));
        }
        // Ps wave-private: lgkmcnt auto-wait orders write->read, no barrier

        #pragma unroll
        for (int kk = 0; kk < 2; kk++) {
            #pragma unroll
            for (int mm = 0; mm < 2; mm++) {
                short8 a = *(const short8*)&Ps[wave * 2304 + (mm * 16 + lane15) * 72 + kk * 32 + quad * 8];
                #pragma unroll
                for (int jn = 0; jn < 4; jn++) {
                    short8 bb = *(const short8*)&Vs[cur][(jn * 16 + lane15) * 64 + (((kk * 4 + quad) ^ sw) * 8)];
                    o[mm][jn] = __builtin_amdgcn_mfma_f32_16x16x32_bf16(a, bb, o[mm][jn], 0, 0, 0);
                }
                o[mm][4] = __builtin_amdgcn_mfma_f32_16x16x32_bf16(a, kOnes, o[mm][4], 0, 0, 0);
            }
        }
    }

    // epilogue: Y = O / l
    #pragma unroll
    for (int mm = 0; mm < 2; mm++)
        #pragma unroll
        for (int r = 0; r < 4; r++) {
            const int qrow = q0 + wave * 32 + mm * 16 + quad * 4 + r;
            const float rinv = 1.0f / fmaxf(o[mm][4][r], 1e-30f);
            #pragma unroll
            for (int jn = 0; jn < 4; jn++)
                QY[baseR + (size_t)qrow * CH + jn * 16 + lane15] = f2b(o[mm][jn][r] * rinv);
        }
}

extern "C" void kernel_launch(void* const* d_in, const int* in_sizes, int n_in,
                              void* d_out, int out_size, void* d_ws, size_t ws_size,
                              hipStream_t stream) {
    const void* x  = d_in[0];
    const void* Wk = d_in[1];
    const void* bk = d_in[2];
    const void* Wq = d_in[3];
    const void* bq = d_in[4];
    const void* Wv = d_in[5];
    const void* bv = d_in[6];
    const void* Wo = d_in[7];
    const void* bo = d_in[8];

    ushort_t* ws    = (ushort_t*)d_ws;
    int*      flag  = (int*)d_ws;
    ushort_t* biasC = ws + 2048;                    // 4x1024: q,k,v,o (contiguous)
    ushort_t* WqkvT = ws + 32768;                   // 3x1M contiguous: q,k,v
    ushort_t* WoT   = WqkvT + 3u * (1u << 20);
    ushort_t* xb    = ws + 4227072;                 // 8M elems bf16
    ushort_t* Qb    = ws + 12615680;                // 8M elems (becomes Y)
    ushort_t* Kb    = (ushort_t*)d_out;             // d_out scratch until final GEMM
    ushort_t* VtB   = Kb + (size_t)MROWS * CH;

    detect_and_bias<<<1, 256, 0, stream>>>((const ushort_t*)x, flag, bq, bk, bv, bo, biasC);

    dim3 tgrid(32, 32, 4);
    convert_wt4<<<tgrid, 256, 0, stream>>>(Wq, Wk, Wv, Wo,
                                           WqkvT, WqkvT + (1u << 20), WqkvT + 2u * (1u << 20), WoT, flag);
    convert_x<<<MROWS * CH / (256 * 8), 256, 0, stream>>>(x, xb, flag);

    // scale = (1/sqrt(64)) * log2(e), folded into Q so attention uses exp2
    dim3 qgrid(MROWS / 128, 3 * CH / 128);
    gemm_qkv<<<qgrid, 256, 0, stream>>>(xb, WqkvT, biasC, Qb, Kb, VtB, 0.1803368801f);

    attn_fwd<<<dim3(1024), 256, 0, stream>>>(Qb, Kb, VtB);

    dim3 ogrid(MROWS / 128, CH / 128);
    gemm_bt<<<ogrid, 256, 0, stream>>>(Qb, WoT, biasC + 3072, d_out, MROWS, CH, CH, flag);
}

// Round 11
// 281.643 us; speedup vs baseline: 1.0011x; 1.0011x over previous
//
#include <hip/hip_runtime.h>
#include <hip/hip_bf16.h>

typedef unsigned short ushort_t;
typedef __attribute__((ext_vector_type(8))) short short8;   // 8 x bf16 (4 VGPRs)
typedef __attribute__((ext_vector_type(4))) float floatx4;  // MFMA acc

#define BATCH 4
#define SEQ   2048
#define CH    1024
#define NHEAD 16
#define HSZ   64
#define MROWS (BATCH * SEQ)  // 8192

// async global->LDS, 16B per lane; LDS dest = wave-uniform base + lane*16
#define GLD16(gptr, lptr) \
    __builtin_amdgcn_global_load_lds((const __attribute__((address_space(1))) unsigned int*)(gptr), \
                                     (__attribute__((address_space(3))) unsigned int*)(lptr), 16, 0, 0)

__device__ inline ushort_t f2b(float f) {
    __hip_bfloat16 h = __float2bfloat16(f);
    return *(ushort_t*)&h;
}
__device__ inline float b2f(ushort_t u) {
    return __bfloat162float(*(__hip_bfloat16*)&u);
}

// -------- fused dtype-detect + bias convert --------------------------------------
__global__ __launch_bounds__(256) void detect_and_bias(const ushort_t* __restrict__ x,
                                                       int* __restrict__ flag,
                                                       const void* b0, const void* b1,
                                                       const void* b2, const void* b3,
                                                       ushort_t* __restrict__ out) {
    __shared__ int sflag;
    if (threadIdx.x < 64) {
        int cnt = 0;
        #pragma unroll
        for (int i = 0; i < 8; i++) {
            const int e = (x[2 * (threadIdx.x * 8 + i)] >> 7) & 0xFF;
            const unsigned long long m = __ballot(e >= 100 && e <= 140);
            cnt += (int)__popcll(m);
        }
        if (threadIdx.x == 0) { sflag = (cnt >= 400) ? 1 : 0; *flag = sflag; }
    }
    __syncthreads();
    const int am = sflag;
    for (int i = threadIdx.x; i < 4096; i += 256) {
        const int m = i >> 10, idx = i & 1023;
        const void* in = (m == 0) ? b0 : (m == 1) ? b1 : (m == 2) ? b2 : b3;
        out[i] = am ? ((const ushort_t*)in)[idx] : f2b(((const float*)in)[idx]);
    }
}

// -------- 4x weight transpose+convert: in[k][n] -> out bf16 [n][k] ---------------
__global__ __launch_bounds__(256) void convert_wt4(const void* w0, const void* w1,
                                                   const void* w2, const void* w3,
                                                   ushort_t* o0, ushort_t* o1,
                                                   ushort_t* o2, ushort_t* o3,
                                                   const int* __restrict__ flag) {
    __shared__ ushort_t tile[32][33];
    const void* in = (blockIdx.z == 0) ? w0 : (blockIdx.z == 1) ? w1 : (blockIdx.z == 2) ? w2 : w3;
    ushort_t*  out = (blockIdx.z == 0) ? o0 : (blockIdx.z == 1) ? o1 : (blockIdx.z == 2) ? o2 : o3;
    const int am = *flag;
    const int bx = blockIdx.x * 32, by = blockIdx.y * 32;
    const int tx = threadIdx.x & 31, ty = threadIdx.x >> 5;
    #pragma unroll
    for (int r = ty; r < 32; r += 8) {
        const size_t idx = (size_t)(by + r) * CH + bx + tx;
        tile[r][tx] = am ? ((const ushort_t*)in)[idx] : f2b(((const float*)in)[idx]);
    }
    __syncthreads();
    #pragma unroll
    for (int r = ty; r < 32; r += 8)
        out[(size_t)(bx + r) * CH + by + tx] = tile[tx][r];
}

// -------- x convert: flat fp32/bf16 -> bf16, 8 elems/thread ----------------------
__global__ __launch_bounds__(256) void convert_x(const void* __restrict__ in,
                                                 ushort_t* __restrict__ out,
                                                 const int* __restrict__ flag) {
    const int i = (blockIdx.x * 256 + threadIdx.x) * 8;
    if (*flag) {
        *(float4*)&out[i] = *(const float4*)&((const ushort_t*)in)[i];
    } else {
        const float* p = (const float*)in + i;
        float4 f0 = *(const float4*)p;
        float4 f1 = *(const float4*)(p + 4);
        ushort_t t[8] = {f2b(f0.x), f2b(f0.y), f2b(f0.z), f2b(f0.w),
                         f2b(f1.x), f2b(f1.y), f2b(f1.z), f2b(f1.w)};
        *(float4*)&out[i] = *(const float4*)t;
    }
}

// ---------------- fused QKV GEMM: [8192,1024] @ [3072,1024]^T + bias -------------
// Round-9 structure (measured best GEMM) + XOR-swizzled LDS to kill the 8-way
// frag-read bank conflicts: physical chunk = logical chunk ^ ((row>>1)&3).
// Write side is free (global address permuted per lane, LDS dest fixed);
// read side: chunk = quad ^ ((lane15>>1)&3) -> 8 groups x 2 lanes = conflict-free.
__global__ __launch_bounds__(256) void gemm_qkv(const ushort_t* __restrict__ A,
                                                const ushort_t* __restrict__ Bt,
                                                const ushort_t* __restrict__ bias,
                                                ushort_t* __restrict__ Qb,
                                                ushort_t* __restrict__ Kb,
                                                ushort_t* __restrict__ Vt,
                                                float qscale) {
    __shared__ __align__(16) ushort_t As[128 * 32];
    __shared__ __align__(16) ushort_t Bs[128 * 32];
    const int K = CH;
    const int tid = threadIdx.x;
    const int lane = tid & 63, wave = tid >> 6;
    const int lane15 = lane & 15, quad = lane >> 4;
    const int wr = (wave >> 1) * 64, wc = (wave & 1) * 64;
    const int row0 = blockIdx.x * 128, col0 = blockIdx.y * 128;
    const int seg = blockIdx.y >> 3;  // 0=Q 1=K 2=V
    const int kg = (lane & 3) ^ ((lane >> 3) & 3);       // staging chunk swizzle
    const int swk = (quad ^ ((lane15 >> 1) & 3)) * 8;    // read chunk swizzle

    floatx4 acc[4][4];
    #pragma unroll
    for (int i = 0; i < 4; i++)
        #pragma unroll
        for (int j = 0; j < 4; j++) acc[i][j] = {0.f, 0.f, 0.f, 0.f};

    for (int k0 = 0; k0 < K; k0 += 32) {
        #pragma unroll
        for (int l = wave; l < 8; l += 4) {
            GLD16(A  + (size_t)(row0 + l * 16 + (lane >> 2)) * K + k0 + kg * 8, &As[l * 512]);
            GLD16(Bt + (size_t)(col0 + l * 16 + (lane >> 2)) * K + k0 + kg * 8, &Bs[l * 512]);
        }
        __syncthreads();
        short8 af[4], bfr[4];
        #pragma unroll
        for (int i = 0; i < 4; i++)
            af[i] = *(const short8*)&As[(wr + i * 16 + lane15) * 32 + swk];
        #pragma unroll
        for (int j = 0; j < 4; j++)
            bfr[j] = *(const short8*)&Bs[(wc + j * 16 + lane15) * 32 + swk];
        #pragma unroll
        for (int i = 0; i < 4; i++)
            #pragma unroll
            for (int j = 0; j < 4; j++)
                acc[i][j] = __builtin_amdgcn_mfma_f32_16x16x32_bf16(af[i], bfr[j], acc[i][j], 0, 0, 0);
        __syncthreads();
    }

    #pragma unroll
    for (int j = 0; j < 4; j++) {
        const int col = col0 + wc + j * 16 + lane15;
        const float bv = b2f(bias[col]);
        #pragma unroll
        for (int i = 0; i < 4; i++) {
            const int rowb = row0 + wr + i * 16 + quad * 4;
            if (seg == 0) {
                #pragma unroll
                for (int r = 0; r < 4; r++)
                    Qb[(size_t)(rowb + r) * CH + col] = f2b((acc[i][j][r] + bv) * qscale);
            } else if (seg == 1) {
                const int c = col - 1024;
                #pragma unroll
                for (int r = 0; r < 4; r++)
                    Kb[(size_t)(rowb + r) * CH + c] = f2b(acc[i][j][r] + bv);
            } else {
                const int c = col - 2048;
                ushort_t pk[4];
                #pragma unroll
                for (int r = 0; r < 4; r++) pk[r] = f2b(acc[i][j][r] + bv);
                const int bb = rowb >> 11, t = rowb & 2047;
                *(uint2*)&Vt[((size_t)bb * 1024 + c) * 2048 + t] = *(const uint2*)pk;
            }
        }
    }
}

// ---------------- output GEMM: Out[M,N] = A @ Bt^T + bias (fp32 or bf16 out) -----
__global__ __launch_bounds__(256) void gemm_bt(const ushort_t* __restrict__ A,
                                               const ushort_t* __restrict__ Bt,
                                               const ushort_t* __restrict__ bias,
                                               void* __restrict__ Out,
                                               int M, int N, int K,
                                               const int* __restrict__ oflag) {
    __shared__ __align__(16) ushort_t As[128 * 32];
    __shared__ __align__(16) ushort_t Bs[128 * 32];
    const int om = *oflag;
    const int tid = threadIdx.x;
    const int lane = tid & 63, wave = tid >> 6;
    const int lane15 = lane & 15, quad = lane >> 4;
    const int wr = (wave >> 1) * 64, wc = (wave & 1) * 64;
    const int row0 = blockIdx.x * 128, col0 = blockIdx.y * 128;
    const int kg = (lane & 3) ^ ((lane >> 3) & 3);       // staging chunk swizzle
    const int swk = (quad ^ ((lane15 >> 1) & 3)) * 8;    // read chunk swizzle

    floatx4 acc[4][4];
    #pragma unroll
    for (int i = 0; i < 4; i++)
        #pragma unroll
        for (int j = 0; j < 4; j++) acc[i][j] = {0.f, 0.f, 0.f, 0.f};

    for (int k0 = 0; k0 < K; k0 += 32) {
        #pragma unroll
        for (int l = wave; l < 8; l += 4) {
            GLD16(A  + (size_t)(row0 + l * 16 + (lane >> 2)) * K + k0 + kg * 8, &As[l * 512]);
            GLD16(Bt + (size_t)(col0 + l * 16 + (lane >> 2)) * K + k0 + kg * 8, &Bs[l * 512]);
        }
        __syncthreads();
        short8 af[4], bfr[4];
        #pragma unroll
        for (int i = 0; i < 4; i++)
            af[i] = *(const short8*)&As[(wr + i * 16 + lane15) * 32 + swk];
        #pragma unroll
        for (int j = 0; j < 4; j++)
            bfr[j] = *(const short8*)&Bs[(wc + j * 16 + lane15) * 32 + swk];
        #pragma unroll
        for (int i = 0; i < 4; i++)
            #pragma unroll
            for (int j = 0; j < 4; j++)
                acc[i][j] = __builtin_amdgcn_mfma_f32_16x16x32_bf16(af[i], bfr[j], acc[i][j], 0, 0, 0);
        __syncthreads();
    }

    #pragma unroll
    for (int j = 0; j < 4; j++) {
        const int col = col0 + wc + j * 16 + lane15;
        const float bv = b2f(bias[col]);
        #pragma unroll
        for (int i = 0; i < 4; i++) {
            const int rowb = row0 + wr + i * 16 + quad * 4;
            #pragma unroll
            for (int r = 0; r < 4; r++) {
                const float val = acc[i][j][r] + bv;
                const size_t idx = (size_t)(rowb + r) * N + col;
                if (om) ((ushort_t*)Out)[idx] = f2b(val);
                else    ((float*)Out)[idx] = val;
            }
        }
    }
}

// ---------------- flash attention (round-6 structure: measured best) -------------
// Ps LDS round-trip decouples the S-phase from PV (overlappable across waves) —
// measured 79-81 us vs 110 us for the register-shuffle S^T form and 240 us for
// the VGPR-clamped variant. Keep: K/V dbuf, one barrier per tile, XCD-local
// (b,h) in bid&63, ones-MFMA rowsum, exp2 with scale folded into Q, swizzled
// K/V staging. DO NOT add a second __launch_bounds__ arg (round-7 spill).
__global__ __launch_bounds__(256) void attn_fwd(ushort_t* __restrict__ QY,
                                                const ushort_t* __restrict__ K,
                                                const ushort_t* __restrict__ Vt) {
    __shared__ __align__(16) ushort_t Ks[2][64 * 64];    // [buf][kv][d], swizzled
    __shared__ __align__(16) ushort_t Vs[2][64 * 64];    // [buf][d][kv], swizzled
    __shared__ __align__(16) ushort_t Ps[4 * 32 * 72];   // per-wave [q=32][kv=64], stride 72
    const int tid = threadIdx.x;
    const int lane = tid & 63, wave = tid >> 6;
    const int lane15 = lane & 15, quad = lane >> 4;
    const int sw = lane15 & 7;                            // read-side swizzle key
    const int bid = blockIdx.x;
    const int hb = bid & 63, qslot = bid >> 6;
    const int qb = 15 - qslot;
    const int h = hb & 15, b = hb >> 4;
    const int q0 = qb * 128;
    const size_t baseR = (size_t)b * SEQ * CH + h * HSZ;      // +t*CH+d (Q,K,Y)
    const size_t baseV = ((size_t)b * 1024 + h * HSZ) * SEQ;  // +d*SEQ+t (Vt)
    const int rg = lane >> 3, cg = (lane & 7) ^ rg;           // staging swizzle

    short8 qf[2][2];
    #pragma unroll
    for (int mm = 0; mm < 2; mm++) {
        const ushort_t* qp = QY + baseR + (size_t)(q0 + wave * 32 + mm * 16 + lane15) * CH + quad * 8;
        qf[mm][0] = *(const short8*)qp;
        qf[mm][1] = *(const short8*)(qp + 32);
    }
    const short8 kOnes = (short8)(short)0x3F80;  // bf16 1.0 x8

    floatx4 o[2][5];  // [mm][0..3]=O d-chunks, [4]=l (rowsum)
    #pragma unroll
    for (int mm = 0; mm < 2; mm++)
        #pragma unroll
        for (int j = 0; j < 5; j++) o[mm][j] = {0.f, 0.f, 0.f, 0.f};

    const int nkt = 2 * qb + 2;
    // preamble: stage tile 0 into buf 0
    #pragma unroll
    for (int l = wave; l < 8; l += 4) {
        GLD16(K  + baseR + (size_t)(l * 8 + rg) * CH + cg * 8, &Ks[0][l * 512]);
        GLD16(Vt + baseV + (size_t)(l * 8 + rg) * SEQ + cg * 8, &Vs[0][l * 512]);
    }

    for (int kt = 0; kt < nkt; kt++) {
        __syncthreads();  // staging of kt landed; all waves done with buf kt^1
        const int cur = kt & 1;
        if (kt + 1 < nkt) {
            const int kv1 = (kt + 1) * 64, nb = cur ^ 1;
            #pragma unroll
            for (int l = wave; l < 8; l += 4) {
                GLD16(K  + baseR + (size_t)(kv1 + l * 8 + rg) * CH + cg * 8, &Ks[nb][l * 512]);
                GLD16(Vt + baseV + (size_t)(l * 8 + rg) * SEQ + kv1 + cg * 8, &Vs[nb][l * 512]);
            }
        }
        const int kv0 = kt * 64;
        const int masked = (kt >= 2 * qb);
        #pragma unroll
        for (int mm = 0; mm < 2; mm++) {
            floatx4 s4[4];
            #pragma unroll
            for (int j = 0; j < 4; j++) {
                short8 b0 = *(const short8*)&Ks[cur][(j * 16 + lane15) * 64 + ((quad ^ sw) * 8)];
                short8 b1 = *(const short8*)&Ks[cur][(j * 16 + lane15) * 64 + (((quad + 4) ^ sw) * 8)];
                floatx4 z = {0.f, 0.f, 0.f, 0.f};
                z = __builtin_amdgcn_mfma_f32_16x16x32_bf16(qf[mm][0], b0, z, 0, 0, 0);
                z = __builtin_amdgcn_mfma_f32_16x16x32_bf16(qf[mm][1], b1, z, 0, 0, 0);
                s4[j] = z;
            }
            const int qrow_base = q0 + wave * 32 + mm * 16 + quad * 4;
            if (masked) {
                #pragma unroll
                for (int j = 0; j < 4; j++) {
                    const int col = kv0 + j * 16 + lane15;
                    #pragma unroll
                    for (int r = 0; r < 4; r++)
                        s4[j][r] = (col <= qrow_base + r) ? s4[j][r] : -1e30f;
                }
            }
            // p = 2^s  (2^-1e30 -> 0 for masked lanes)
            #pragma unroll
            for (int j = 0; j < 4; j++)
                #pragma unroll
                for (int r = 0; r < 4; r++)
                    Ps[wave * 2304 + (mm * 16 + quad * 4 + r) * 72 + j * 16 + lane15] =
                        f2b(exp2f(s4[j][r]));
        }
        // Ps wave-private: lgkmcnt auto-wait orders write->read, no barrier

        #pragma unroll
        for (int kk = 0; kk < 2; kk++) {
            #pragma unroll
            for (int mm = 0; mm < 2; mm++) {
                short8 a = *(const short8*)&Ps[wave * 2304 + (mm * 16 + lane15) * 72 + kk * 32 + quad * 8];
                #pragma unroll
                for (int jn = 0; jn < 4; jn++) {
                    short8 bb = *(const short8*)&Vs[cur][(jn * 16 + lane15) * 64 + (((kk * 4 + quad) ^ sw) * 8)];
                    o[mm][jn] = __builtin_amdgcn_mfma_f32_16x16x32_bf16(a, bb, o[mm][jn], 0, 0, 0);
                }
                o[mm][4] = __builtin_amdgcn_mfma_f32_16x16x32_bf16(a, kOnes, o[mm][4], 0, 0, 0);
            }
        }
    }

    // epilogue: Y = O / l
    #pragma unroll
    for (int mm = 0; mm < 2; mm++)
        #pragma unroll
        for (int r = 0; r < 4; r++) {
            const int qrow = q0 + wave * 32 + mm * 16 + quad * 4 + r;
            const float rinv = 1.0f / fmaxf(o[mm][4][r], 1e-30f);
            #pragma unroll
            for (int jn = 0; jn < 4; jn++)
                QY[baseR + (size_t)qrow * CH + jn * 16 + lane15] = f2b(o[mm][jn][r] * rinv);
        }
}

extern "C" void kernel_launch(void* const* d_in, const int* in_sizes, int n_in,
                              void* d_out, int out_size, void* d_ws, size_t ws_size,
                              hipStream_t stream) {
    const void* x  = d_in[0];
    const void* Wk = d_in[1];
    const void* bk = d_in[2];
    const void* Wq = d_in[3];
    const void* bq = d_in[4];
    const void* Wv = d_in[5];
    const void* bv = d_in[6];
    const void* Wo = d_in[7];
    const void* bo = d_in[8];

    ushort_t* ws    = (ushort_t*)d_ws;
    int*      flag  = (int*)d_ws;
    ushort_t* biasC = ws + 2048;                    // 4x1024: q,k,v,o (contiguous)
    ushort_t* WqkvT = ws + 32768;                   // 3x1M contiguous: q,k,v
    ushort_t* WoT   = WqkvT + 3u * (1u << 20);
    ushort_t* xb    = ws + 4227072;                 // 8M elems bf16
    ushort_t* Qb    = ws + 12615680;                // 8M elems (becomes Y)
    ushort_t* Kb    = (ushort_t*)d_out;             // d_out scratch until final GEMM
    ushort_t* VtB   = Kb + (size_t)MROWS * CH;

    detect_and_bias<<<1, 256, 0, stream>>>((const ushort_t*)x, flag, bq, bk, bv, bo, biasC);

    dim3 tgrid(32, 32, 4);
    convert_wt4<<<tgrid, 256, 0, stream>>>(Wq, Wk, Wv, Wo,
                                           WqkvT, WqkvT + (1u << 20), WqkvT + 2u * (1u << 20), WoT, flag);
    convert_x<<<MROWS * CH / (256 * 8), 256, 0, stream>>>(x, xb, flag);

    // scale = (1/sqrt(64)) * log2(e), folded into Q so attention uses exp2
    dim3 qgrid(MROWS / 128, 3 * CH / 128);
    gemm_qkv<<<qgrid, 256, 0, stream>>>(xb, WqkvT, biasC, Qb, Kb, VtB, 0.1803368801f);

    attn_fwd<<<dim3(1024), 256, 0, stream>>>(Qb, Kb, VtB);

    dim3 ogrid(MROWS / 128, CH / 128);
    gemm_bt<<<ogrid, 256, 0, stream>>>(Qb, WoT, biasC + 3072, d_out, MROWS, CH, CH, flag);
}

// Round 12
// 271.623 us; speedup vs baseline: 1.0380x; 1.0369x over previous
//
#include <hip/hip_runtime.h>
#include <hip/hip_bf16.h>

typedef unsigned short ushort_t;
typedef __attribute__((ext_vector_type(8))) short short8;   // 8 x bf16 (4 VGPRs)
typedef __attribute__((ext_vector_type(4))) float floatx4;  // MFMA acc

#define BATCH 4
#define SEQ   2048
#define CH    1024
#define NHEAD 16
#define HSZ   64
#define MROWS (BATCH * SEQ)  // 8192

// async global->LDS, 16B per lane; LDS dest = wave-uniform base + lane*16
#define GLD16(gptr, lptr) \
    __builtin_amdgcn_global_load_lds((const __attribute__((address_space(1))) unsigned int*)(gptr), \
                                     (__attribute__((address_space(3))) unsigned int*)(lptr), 16, 0, 0)

__device__ inline ushort_t f2b(float f) {
    __hip_bfloat16 h = __float2bfloat16(f);
    return *(ushort_t*)&h;
}
__device__ inline float b2f(ushort_t u) {
    return __bfloat162float(*(__hip_bfloat16*)&u);
}

// -------- dtype detect (parallel): *flag = 1 if x is bf16, 0 if f32 --------------
__global__ void detect_dtype(const ushort_t* __restrict__ x, int* __restrict__ flag) {
    int cnt = 0;
    #pragma unroll
    for (int i = 0; i < 8; i++) {
        const int e = (x[2 * (threadIdx.x * 8 + i)] >> 7) & 0xFF;
        const unsigned long long m = __ballot(e >= 100 && e <= 140);
        cnt += (int)__popcll(m);
    }
    if (threadIdx.x == 0) *flag = (cnt >= 400) ? 1 : 0;
}

// -------- 4x weight transpose+convert: in[k][n] -> out bf16 [n][k] ---------------
__global__ __launch_bounds__(256) void convert_wt4(const void* w0, const void* w1,
                                                   const void* w2, const void* w3,
                                                   ushort_t* o0, ushort_t* o1,
                                                   ushort_t* o2, ushort_t* o3,
                                                   const int* __restrict__ flag) {
    __shared__ ushort_t tile[32][33];
    const void* in = (blockIdx.z == 0) ? w0 : (blockIdx.z == 1) ? w1 : (blockIdx.z == 2) ? w2 : w3;
    ushort_t*  out = (blockIdx.z == 0) ? o0 : (blockIdx.z == 1) ? o1 : (blockIdx.z == 2) ? o2 : o3;
    const int am = *flag;
    const int bx = blockIdx.x * 32, by = blockIdx.y * 32;
    const int tx = threadIdx.x & 31, ty = threadIdx.x >> 5;
    #pragma unroll
    for (int r = ty; r < 32; r += 8) {
        const size_t idx = (size_t)(by + r) * CH + bx + tx;
        tile[r][tx] = am ? ((const ushort_t*)in)[idx] : f2b(((const float*)in)[idx]);
    }
    __syncthreads();
    #pragma unroll
    for (int r = ty; r < 32; r += 8)
        out[(size_t)(bx + r) * CH + by + tx] = tile[tx][r];
}

// -------- 4x bias convert --------------------------------------------------------
__global__ void convert_bias4(const void* b0, const void* b1, const void* b2, const void* b3,
                              ushort_t* __restrict__ out, const int* __restrict__ flag) {
    const int i = blockIdx.x * 256 + threadIdx.x;  // 0..4095
    const int m = i >> 10, idx = i & 1023;
    const void* in = (m == 0) ? b0 : (m == 1) ? b1 : (m == 2) ? b2 : b3;
    out[i] = (*flag) ? ((const ushort_t*)in)[idx] : f2b(((const float*)in)[idx]);
}

// -------- x convert: flat fp32/bf16 -> bf16, 8 elems/thread ----------------------
__global__ __launch_bounds__(256) void convert_x(const void* __restrict__ in,
                                                 ushort_t* __restrict__ out,
                                                 const int* __restrict__ flag) {
    const int i = (blockIdx.x * 256 + threadIdx.x) * 8;
    if (*flag) {
        *(float4*)&out[i] = *(const float4*)&((const ushort_t*)in)[i];
    } else {
        const float* p = (const float*)in + i;
        float4 f0 = *(const float4*)p;
        float4 f1 = *(const float4*)(p + 4);
        ushort_t t[8] = {f2b(f0.x), f2b(f0.y), f2b(f0.z), f2b(f0.w),
                         f2b(f1.x), f2b(f1.y), f2b(f1.z), f2b(f1.w)};
        *(float4*)&out[i] = *(const float4*)t;
    }
}

// ---------------- fused QKV GEMM: [8192,1024] @ [3072,1024]^T + bias -------------
// Column segment (blockIdx.y>>3): 0 -> Qb row-major *qscale; 1 -> Kb row-major;
// 2 -> Vt[b][n][t] transposed-per-head. Branch is block-uniform.
__global__ __launch_bounds__(256) void gemm_qkv(const ushort_t* __restrict__ A,
                                                const ushort_t* __restrict__ Bt,
                                                const ushort_t* __restrict__ bias,
                                                ushort_t* __restrict__ Qb,
                                                ushort_t* __restrict__ Kb,
                                                ushort_t* __restrict__ Vt,
                                                float qscale) {
    __shared__ __align__(16) ushort_t As[128 * 32];
    __shared__ __align__(16) ushort_t Bs[128 * 32];
    const int K = CH;
    const int tid = threadIdx.x;
    const int lane = tid & 63, wave = tid >> 6;
    const int lane15 = lane & 15, quad = lane >> 4;
    const int wr = (wave >> 1) * 64, wc = (wave & 1) * 64;
    const int row0 = blockIdx.x * 128, col0 = blockIdx.y * 128;
    const int seg = blockIdx.y >> 3;  // 0=Q 1=K 2=V

    floatx4 acc[4][4];
    #pragma unroll
    for (int i = 0; i < 4; i++)
        #pragma unroll
        for (int j = 0; j < 4; j++) acc[i][j] = {0.f, 0.f, 0.f, 0.f};

    for (int k0 = 0; k0 < K; k0 += 32) {
        #pragma unroll
        for (int l = wave; l < 8; l += 4) {
            GLD16(A  + (size_t)(row0 + l * 16 + (lane >> 2)) * K + k0 + (lane & 3) * 8, &As[l * 512]);
            GLD16(Bt + (size_t)(col0 + l * 16 + (lane >> 2)) * K + k0 + (lane & 3) * 8, &Bs[l * 512]);
        }
        __syncthreads();
        short8 af[4], bfr[4];
        #pragma unroll
        for (int i = 0; i < 4; i++)
            af[i] = *(const short8*)&As[(wr + i * 16 + lane15) * 32 + quad * 8];
        #pragma unroll
        for (int j = 0; j < 4; j++)
            bfr[j] = *(const short8*)&Bs[(wc + j * 16 + lane15) * 32 + quad * 8];
        #pragma unroll
        for (int i = 0; i < 4; i++)
            #pragma unroll
            for (int j = 0; j < 4; j++)
                acc[i][j] = __builtin_amdgcn_mfma_f32_16x16x32_bf16(af[i], bfr[j], acc[i][j], 0, 0, 0);
        __syncthreads();
    }

    #pragma unroll
    for (int j = 0; j < 4; j++) {
        const int col = col0 + wc + j * 16 + lane15;
        const float bv = b2f(bias[col]);
        #pragma unroll
        for (int i = 0; i < 4; i++) {
            const int rowb = row0 + wr + i * 16 + quad * 4;
            if (seg == 0) {
                #pragma unroll
                for (int r = 0; r < 4; r++)
                    Qb[(size_t)(rowb + r) * CH + col] = f2b((acc[i][j][r] + bv) * qscale);
            } else if (seg == 1) {
                const int c = col - 1024;
                #pragma unroll
                for (int r = 0; r < 4; r++)
                    Kb[(size_t)(rowb + r) * CH + c] = f2b(acc[i][j][r] + bv);
            } else {
                const int c = col - 2048;
                ushort_t pk[4];
                #pragma unroll
                for (int r = 0; r < 4; r++) pk[r] = f2b(acc[i][j][r] + bv);
                const int bb = rowb >> 11, t = rowb & 2047;
                *(uint2*)&Vt[((size_t)bb * 1024 + c) * 2048 + t] = *(const uint2*)pk;
            }
        }
    }
}

// ---------------- output GEMM: Out[M,N] = A @ Bt^T + bias (fp32 or bf16 out) -----
__global__ __launch_bounds__(256) void gemm_bt(const ushort_t* __restrict__ A,
                                               const ushort_t* __restrict__ Bt,
                                               const ushort_t* __restrict__ bias,
                                               void* __restrict__ Out,
                                               int M, int N, int K,
                                               const int* __restrict__ oflag) {
    __shared__ __align__(16) ushort_t As[128 * 32];
    __shared__ __align__(16) ushort_t Bs[128 * 32];
    const int om = *oflag;
    const int tid = threadIdx.x;
    const int lane = tid & 63, wave = tid >> 6;
    const int lane15 = lane & 15, quad = lane >> 4;
    const int wr = (wave >> 1) * 64, wc = (wave & 1) * 64;
    const int row0 = blockIdx.x * 128, col0 = blockIdx.y * 128;

    floatx4 acc[4][4];
    #pragma unroll
    for (int i = 0; i < 4; i++)
        #pragma unroll
        for (int j = 0; j < 4; j++) acc[i][j] = {0.f, 0.f, 0.f, 0.f};

    for (int k0 = 0; k0 < K; k0 += 32) {
        #pragma unroll
        for (int l = wave; l < 8; l += 4) {
            GLD16(A  + (size_t)(row0 + l * 16 + (lane >> 2)) * K + k0 + (lane & 3) * 8, &As[l * 512]);
            GLD16(Bt + (size_t)(col0 + l * 16 + (lane >> 2)) * K + k0 + (lane & 3) * 8, &Bs[l * 512]);
        }
        __syncthreads();
        short8 af[4], bfr[4];
        #pragma unroll
        for (int i = 0; i < 4; i++)
            af[i] = *(const short8*)&As[(wr + i * 16 + lane15) * 32 + quad * 8];
        #pragma unroll
        for (int j = 0; j < 4; j++)
            bfr[j] = *(const short8*)&Bs[(wc + j * 16 + lane15) * 32 + quad * 8];
        #pragma unroll
        for (int i = 0; i < 4; i++)
            #pragma unroll
            for (int j = 0; j < 4; j++)
                acc[i][j] = __builtin_amdgcn_mfma_f32_16x16x32_bf16(af[i], bfr[j], acc[i][j], 0, 0, 0);
        __syncthreads();
    }

    #pragma unroll
    for (int j = 0; j < 4; j++) {
        const int col = col0 + wc + j * 16 + lane15;
        const float bv = b2f(bias[col]);
        #pragma unroll
        for (int i = 0; i < 4; i++) {
            const int rowb = row0 + wr + i * 16 + quad * 4;
            #pragma unroll
            for (int r = 0; r < 4; r++) {
                const float val = acc[i][j][r] + bv;
                const size_t idx = (size_t)(rowb + r) * N + col;
                if (om) ((ushort_t*)Out)[idx] = f2b(val);
                else    ((float*)Out)[idx] = val;
            }
        }
    }
}

// ---------------- flash attention (round-6 structure: measured best) -------------
// Ps LDS round-trip decouples the S-phase from PV (overlappable across waves) —
// measured 79-81 us vs 110 us for the register-shuffle S^T form and 240 us for
// the VGPR-clamped variant. Keep: K/V dbuf, one barrier per tile, XCD-local
// (b,h) in bid&63, ones-MFMA rowsum, exp2 with scale folded into Q, swizzled
// K/V staging. DO NOT add a second __launch_bounds__ arg (round-7 spill).
__global__ __launch_bounds__(256) void attn_fwd(ushort_t* __restrict__ QY,
                                                const ushort_t* __restrict__ K,
                                                const ushort_t* __restrict__ Vt) {
    __shared__ __align__(16) ushort_t Ks[2][64 * 64];    // [buf][kv][d], swizzled
    __shared__ __align__(16) ushort_t Vs[2][64 * 64];    // [buf][d][kv], swizzled
    __shared__ __align__(16) ushort_t Ps[4 * 32 * 72];   // per-wave [q=32][kv=64], stride 72
    const int tid = threadIdx.x;
    const int lane = tid & 63, wave = tid >> 6;
    const int lane15 = lane & 15, quad = lane >> 4;
    const int sw = lane15 & 7;                            // read-side swizzle key
    const int bid = blockIdx.x;
    const int hb = bid & 63, qslot = bid >> 6;
    const int qb = 15 - qslot;
    const int h = hb & 15, b = hb >> 4;
    const int q0 = qb * 128;
    const size_t baseR = (size_t)b * SEQ * CH + h * HSZ;      // +t*CH+d (Q,K,Y)
    const size_t baseV = ((size_t)b * 1024 + h * HSZ) * SEQ;  // +d*SEQ+t (Vt)
    const int rg = lane >> 3, cg = (lane & 7) ^ rg;           // staging swizzle

    short8 qf[2][2];
    #pragma unroll
    for (int mm = 0; mm < 2; mm++) {
        const ushort_t* qp = QY + baseR + (size_t)(q0 + wave * 32 + mm * 16 + lane15) * CH + quad * 8;
        qf[mm][0] = *(const short8*)qp;
        qf[mm][1] = *(const short8*)(qp + 32);
    }
    const short8 kOnes = (short8)(short)0x3F80;  // bf16 1.0 x8

    floatx4 o[2][5];  // [mm][0..3]=O d-chunks, [4]=l (rowsum)
    #pragma unroll
    for (int mm = 0; mm < 2; mm++)
        #pragma unroll
        for (int j = 0; j < 5; j++) o[mm][j] = {0.f, 0.f, 0.f, 0.f};

    const int nkt = 2 * qb + 2;
    // preamble: stage tile 0 into buf 0
    #pragma unroll
    for (int l = wave; l < 8; l += 4) {
        GLD16(K  + baseR + (size_t)(l * 8 + rg) * CH + cg * 8, &Ks[0][l * 512]);
        GLD16(Vt + baseV + (size_t)(l * 8 + rg) * SEQ + cg * 8, &Vs[0][l * 512]);
    }

    for (int kt = 0; kt < nkt; kt++) {
        __syncthreads();  // staging of kt landed; all waves done with buf kt^1
        const int cur = kt & 1;
        if (kt + 1 < nkt) {
            const int kv1 = (kt + 1) * 64, nb = cur ^ 1;
            #pragma unroll
            for (int l = wave; l < 8; l += 4) {
                GLD16(K  + baseR + (size_t)(kv1 + l * 8 + rg) * CH + cg * 8, &Ks[nb][l * 512]);
                GLD16(Vt + baseV + (size_t)(l * 8 + rg) * SEQ + kv1 + cg * 8, &Vs[nb][l * 512]);
            }
        }
        const int kv0 = kt * 64;
        const int masked = (kt >= 2 * qb);
        #pragma unroll
        for (int mm = 0; mm < 2; mm++) {
            floatx4 s4[4];
            #pragma unroll
            for (int j = 0; j < 4; j++) {
                short8 b0 = *(const short8*)&Ks[cur][(j * 16 + lane15) * 64 + ((quad ^ sw) * 8)];
                short8 b1 = *(const short8*)&Ks[cur][(j * 16 + lane15) * 64 + (((quad + 4) ^ sw) * 8)];
                floatx4 z = {0.f, 0.f, 0.f, 0.f};
                z = __builtin_amdgcn_mfma_f32_16x16x32_bf16(qf[mm][0], b0, z, 0, 0, 0);
                z = __builtin_amdgcn_mfma_f32_16x16x32_bf16(qf[mm][1], b1, z, 0, 0, 0);
                s4[j] = z;
            }
            const int qrow_base = q0 + wave * 32 + mm * 16 + quad * 4;
            if (masked) {
                #pragma unroll
                for (int j = 0; j < 4; j++) {
                    const int col = kv0 + j * 16 + lane15;
                    #pragma unroll
                    for (int r = 0; r < 4; r++)
                        s4[j][r] = (col <= qrow_base + r) ? s4[j][r] : -1e30f;
                }
            }
            // p = 2^s  (2^-1e30 -> 0 for masked lanes)
            #pragma unroll
            for (int j = 0; j < 4; j++)
                #pragma unroll
                for (int r = 0; r < 4; r++)
                    Ps[wave * 2304 + (mm * 16 + quad * 4 + r) * 72 + j * 16 + lane15] =
                        f2b(exp2f(s4[j][r]));
        }
        // Ps wave-private: lgkmcnt auto-wait orders write->read, no barrier

        #pragma unroll
        for (int kk = 0; kk < 2; kk++) {
            #pragma unroll
            for (int mm = 0; mm < 2; mm++) {
                short8 a = *(const short8*)&Ps[wave * 2304 + (mm * 16 + lane15) * 72 + kk * 32 + quad * 8];
                #pragma unroll
                for (int jn = 0; jn < 4; jn++) {
                    short8 bb = *(const short8*)&Vs[cur][(jn * 16 + lane15) * 64 + (((kk * 4 + quad) ^ sw) * 8)];
                    o[mm][jn] = __builtin_amdgcn_mfma_f32_16x16x32_bf16(a, bb, o[mm][jn], 0, 0, 0);
                }
                o[mm][4] = __builtin_amdgcn_mfma_f32_16x16x32_bf16(a, kOnes, o[mm][4], 0, 0, 0);
            }
        }
    }

    // epilogue: Y = O / l
    #pragma unroll
    for (int mm = 0; mm < 2; mm++)
        #pragma unroll
        for (int r = 0; r < 4; r++) {
            const int qrow = q0 + wave * 32 + mm * 16 + quad * 4 + r;
            const float rinv = 1.0f / fmaxf(o[mm][4][r], 1e-30f);
            #pragma unroll
            for (int jn = 0; jn < 4; jn++)
                QY[baseR + (size_t)qrow * CH + jn * 16 + lane15] = f2b(o[mm][jn][r] * rinv);
        }
}

extern "C" void kernel_launch(void* const* d_in, const int* in_sizes, int n_in,
                              void* d_out, int out_size, void* d_ws, size_t ws_size,
                              hipStream_t stream) {
    const void* x  = d_in[0];
    const void* Wk = d_in[1];
    const void* bk = d_in[2];
    const void* Wq = d_in[3];
    const void* bq = d_in[4];
    const void* Wv = d_in[5];
    const void* bv = d_in[6];
    const void* Wo = d_in[7];
    const void* bo = d_in[8];

    ushort_t* ws    = (ushort_t*)d_ws;
    int*      flag  = (int*)d_ws;
    ushort_t* biasC = ws + 2048;                    // 4x1024: q,k,v,o (contiguous)
    ushort_t* WqkvT = ws + 32768;                   // 3x1M contiguous: q,k,v
    ushort_t* WoT   = WqkvT + 3u * (1u << 20);
    ushort_t* xb    = ws + 4227072;                 // 8M elems bf16
    ushort_t* Qb    = ws + 12615680;                // 8M elems (becomes Y)
    ushort_t* Kb    = (ushort_t*)d_out;             // d_out scratch until final GEMM
    ushort_t* VtB   = Kb + (size_t)MROWS * CH;

    detect_dtype<<<1, 64, 0, stream>>>((const ushort_t*)x, flag);

    dim3 tgrid(32, 32, 4);
    convert_wt4<<<tgrid, 256, 0, stream>>>(Wq, Wk, Wv, Wo,
                                           WqkvT, WqkvT + (1u << 20), WqkvT + 2u * (1u << 20), WoT, flag);
    convert_bias4<<<16, 256, 0, stream>>>(bq, bk, bv, bo, biasC, flag);
    convert_x<<<MROWS * CH / (256 * 8), 256, 0, stream>>>(x, xb, flag);

    // scale = (1/sqrt(64)) * log2(e), folded into Q so attention uses exp2
    dim3 qgrid(MROWS / 128, 3 * CH / 128);
    gemm_qkv<<<qgrid, 256, 0, stream>>>(xb, WqkvT, biasC, Qb, Kb, VtB, 0.1803368801f);

    attn_fwd<<<dim3(1024), 256, 0, stream>>>(Qb, Kb, VtB);

    dim3 ogrid(MROWS / 128, CH / 128);
    gemm_bt<<<ogrid, 256, 0, stream>>>(Qb, WoT, biasC + 3072, d_out, MROWS, CH, CH, flag);
}

// Round 13
// 268.477 us; speedup vs baseline: 1.0502x; 1.0117x over previous
//
#include <hip/hip_runtime.h>
#include <hip/hip_bf16.h>

typedef unsigned short ushort_t;
typedef __attribute__((ext_vector_type(8))) short short8;   // 8 x bf16 (4 VGPRs)
typedef __attribute__((ext_vector_type(4))) float floatx4;  // MFMA acc

#define BATCH 4
#define SEQ   2048
#define CH    1024
#define NHEAD 16
#define HSZ   64
#define MROWS (BATCH * SEQ)  // 8192

// async global->LDS, 16B per lane; LDS dest = wave-uniform base + lane*16
#define GLD16(gptr, lptr) \
    __builtin_amdgcn_global_load_lds((const __attribute__((address_space(1))) unsigned int*)(gptr), \
                                     (__attribute__((address_space(3))) unsigned int*)(lptr), 16, 0, 0)

__device__ inline ushort_t f2b(float f) {
    __hip_bfloat16 h = __float2bfloat16(f);
    return *(ushort_t*)&h;
}
__device__ inline float b2f(ushort_t u) {
    return __bfloat162float(*(__hip_bfloat16*)&u);
}

// -------- dtype detect (parallel): *flag = 1 if x is bf16, 0 if f32 --------------
__global__ void detect_dtype(const ushort_t* __restrict__ x, int* __restrict__ flag) {
    int cnt = 0;
    #pragma unroll
    for (int i = 0; i < 8; i++) {
        const int e = (x[2 * (threadIdx.x * 8 + i)] >> 7) & 0xFF;
        const unsigned long long m = __ballot(e >= 100 && e <= 140);
        cnt += (int)__popcll(m);
    }
    if (threadIdx.x == 0) *flag = (cnt >= 400) ? 1 : 0;
}

// -------- 4x weight transpose+convert: in[k][n] -> out bf16 [n][k] ---------------
__global__ __launch_bounds__(256) void convert_wt4(const void* w0, const void* w1,
                                                   const void* w2, const void* w3,
                                                   ushort_t* o0, ushort_t* o1,
                                                   ushort_t* o2, ushort_t* o3,
                                                   const int* __restrict__ flag) {
    __shared__ ushort_t tile[32][33];
    const void* in = (blockIdx.z == 0) ? w0 : (blockIdx.z == 1) ? w1 : (blockIdx.z == 2) ? w2 : w3;
    ushort_t*  out = (blockIdx.z == 0) ? o0 : (blockIdx.z == 1) ? o1 : (blockIdx.z == 2) ? o2 : o3;
    const int am = *flag;
    const int bx = blockIdx.x * 32, by = blockIdx.y * 32;
    const int tx = threadIdx.x & 31, ty = threadIdx.x >> 5;
    #pragma unroll
    for (int r = ty; r < 32; r += 8) {
        const size_t idx = (size_t)(by + r) * CH + bx + tx;
        tile[r][tx] = am ? ((const ushort_t*)in)[idx] : f2b(((const float*)in)[idx]);
    }
    __syncthreads();
    #pragma unroll
    for (int r = ty; r < 32; r += 8)
        out[(size_t)(bx + r) * CH + by + tx] = tile[tx][r];
}

// -------- 4x bias convert --------------------------------------------------------
__global__ void convert_bias4(const void* b0, const void* b1, const void* b2, const void* b3,
                              ushort_t* __restrict__ out, const int* __restrict__ flag) {
    const int i = blockIdx.x * 256 + threadIdx.x;  // 0..4095
    const int m = i >> 10, idx = i & 1023;
    const void* in = (m == 0) ? b0 : (m == 1) ? b1 : (m == 2) ? b2 : b3;
    out[i] = (*flag) ? ((const ushort_t*)in)[idx] : f2b(((const float*)in)[idx]);
}

// -------- x convert: flat fp32/bf16 -> bf16, 8 elems/thread ----------------------
__global__ __launch_bounds__(256) void convert_x(const void* __restrict__ in,
                                                 ushort_t* __restrict__ out,
                                                 const int* __restrict__ flag) {
    const int i = (blockIdx.x * 256 + threadIdx.x) * 8;
    if (*flag) {
        *(float4*)&out[i] = *(const float4*)&((const ushort_t*)in)[i];
    } else {
        const float* p = (const float*)in + i;
        float4 f0 = *(const float4*)p;
        float4 f1 = *(const float4*)(p + 4);
        ushort_t t[8] = {f2b(f0.x), f2b(f0.y), f2b(f0.z), f2b(f0.w),
                         f2b(f1.x), f2b(f1.y), f2b(f1.z), f2b(f1.w)};
        *(float4*)&out[i] = *(const float4*)t;
    }
}

// -------- BK=64 XOR-swizzled K-loop (shared by both GEMMs) -----------------------
// K=1024 -> 16 iterations (was 32): half the vmcnt(0)+barrier drains, 32 MFMA
// per iteration. 128-B LDS rows would be 16-way bank-conflicted on b128 frag
// reads, so staging XOR-permutes chunks: phys = logical ^ (row&7); reads use
// chunk (kk*4+quad)^(lane15&7) -> 2 lanes/bank = free (m136). LDS 2x16KB=32KB.
__device__ __forceinline__ void kloop64(const ushort_t* __restrict__ A,
                                        const ushort_t* __restrict__ Bt,
                                        int K, int row0, int col0,
                                        ushort_t* As, ushort_t* Bs,
                                        floatx4 acc[4][4],
                                        int lane, int wave) {
    const int lane15 = lane & 15, quad = lane >> 4;
    const int wr = (wave >> 1) * 64, wc = (wave & 1) * 64;
    const int rg = lane >> 3;                       // row within 8-row group
    const int cg = (lane & 7) ^ rg;                 // staged (permuted) chunk
    const int s7 = lane15 & 7;                      // read-side swizzle key
    for (int k0 = 0; k0 < K; k0 += 64) {
        #pragma unroll
        for (int l = wave; l < 16; l += 4) {        // 16 wave-loads each (8 rows x 1KB)
            GLD16(A  + (size_t)(row0 + l * 8 + rg) * K + k0 + cg * 8, &As[l * 512]);
            GLD16(Bt + (size_t)(col0 + l * 8 + rg) * K + k0 + cg * 8, &Bs[l * 512]);
        }
        __syncthreads();
        #pragma unroll
        for (int kk = 0; kk < 2; kk++) {
            short8 af[4], bfr[4];
            #pragma unroll
            for (int i = 0; i < 4; i++)
                af[i] = *(const short8*)&As[(wr + i * 16 + lane15) * 64 + (((kk * 4 + quad) ^ s7) * 8)];
            #pragma unroll
            for (int j = 0; j < 4; j++)
                bfr[j] = *(const short8*)&Bs[(wc + j * 16 + lane15) * 64 + (((kk * 4 + quad) ^ s7) * 8)];
            #pragma unroll
            for (int i = 0; i < 4; i++)
                #pragma unroll
                for (int j = 0; j < 4; j++)
                    acc[i][j] = __builtin_amdgcn_mfma_f32_16x16x32_bf16(af[i], bfr[j], acc[i][j], 0, 0, 0);
        }
        __syncthreads();
    }
}

// ---------------- fused QKV GEMM: [8192,1024] @ [3072,1024]^T + bias -------------
// Column segment (blockIdx.y>>3): 0 -> Qb row-major *qscale; 1 -> Kb row-major;
// 2 -> Vt[b][n][t] transposed-per-head. Branch is block-uniform.
__global__ __launch_bounds__(256) void gemm_qkv(const ushort_t* __restrict__ A,
                                                const ushort_t* __restrict__ Bt,
                                                const ushort_t* __restrict__ bias,
                                                ushort_t* __restrict__ Qb,
                                                ushort_t* __restrict__ Kb,
                                                ushort_t* __restrict__ Vt,
                                                float qscale) {
    __shared__ __align__(16) ushort_t As[128 * 64];
    __shared__ __align__(16) ushort_t Bs[128 * 64];
    const int tid = threadIdx.x;
    const int lane = tid & 63, wave = tid >> 6;
    const int lane15 = lane & 15, quad = lane >> 4;
    const int wr = (wave >> 1) * 64, wc = (wave & 1) * 64;
    const int row0 = blockIdx.x * 128, col0 = blockIdx.y * 128;
    const int seg = blockIdx.y >> 3;  // 0=Q 1=K 2=V

    floatx4 acc[4][4];
    #pragma unroll
    for (int i = 0; i < 4; i++)
        #pragma unroll
        for (int j = 0; j < 4; j++) acc[i][j] = {0.f, 0.f, 0.f, 0.f};

    kloop64(A, Bt, CH, row0, col0, As, Bs, acc, lane, wave);

    #pragma unroll
    for (int j = 0; j < 4; j++) {
        const int col = col0 + wc + j * 16 + lane15;
        const float bv = b2f(bias[col]);
        #pragma unroll
        for (int i = 0; i < 4; i++) {
            const int rowb = row0 + wr + i * 16 + quad * 4;
            if (seg == 0) {
                #pragma unroll
                for (int r = 0; r < 4; r++)
                    Qb[(size_t)(rowb + r) * CH + col] = f2b((acc[i][j][r] + bv) * qscale);
            } else if (seg == 1) {
                const int c = col - 1024;
                #pragma unroll
                for (int r = 0; r < 4; r++)
                    Kb[(size_t)(rowb + r) * CH + c] = f2b(acc[i][j][r] + bv);
            } else {
                const int c = col - 2048;
                ushort_t pk[4];
                #pragma unroll
                for (int r = 0; r < 4; r++) pk[r] = f2b(acc[i][j][r] + bv);
                const int bb = rowb >> 11, t = rowb & 2047;
                *(uint2*)&Vt[((size_t)bb * 1024 + c) * 2048 + t] = *(const uint2*)pk;
            }
        }
    }
}

// ---------------- output GEMM: Out[M,N] = A @ Bt^T + bias (fp32 or bf16 out) -----
__global__ __launch_bounds__(256) void gemm_bt(const ushort_t* __restrict__ A,
                                               const ushort_t* __restrict__ Bt,
                                               const ushort_t* __restrict__ bias,
                                               void* __restrict__ Out,
                                               int M, int N, int K,
                                               const int* __restrict__ oflag) {
    __shared__ __align__(16) ushort_t As[128 * 64];
    __shared__ __align__(16) ushort_t Bs[128 * 64];
    const int om = *oflag;
    const int tid = threadIdx.x;
    const int lane = tid & 63, wave = tid >> 6;
    const int lane15 = lane & 15, quad = lane >> 4;
    const int wr = (wave >> 1) * 64, wc = (wave & 1) * 64;
    const int row0 = blockIdx.x * 128, col0 = blockIdx.y * 128;

    floatx4 acc[4][4];
    #pragma unroll
    for (int i = 0; i < 4; i++)
        #pragma unroll
        for (int j = 0; j < 4; j++) acc[i][j] = {0.f, 0.f, 0.f, 0.f};

    kloop64(A, Bt, K, row0, col0, As, Bs, acc, lane, wave);

    #pragma unroll
    for (int j = 0; j < 4; j++) {
        const int col = col0 + wc + j * 16 + lane15;
        const float bv = b2f(bias[col]);
        #pragma unroll
        for (int i = 0; i < 4; i++) {
            const int rowb = row0 + wr + i * 16 + quad * 4;
            #pragma unroll
            for (int r = 0; r < 4; r++) {
                const float val = acc[i][j][r] + bv;
                const size_t idx = (size_t)(rowb + r) * N + col;
                if (om) ((ushort_t*)Out)[idx] = f2b(val);
                else    ((float*)Out)[idx] = val;
            }
        }
    }
}

// ---------------- flash attention (round-6 structure: measured best) -------------
// Ps LDS round-trip decouples the S-phase from PV (overlappable across waves) —
// measured 79-81 us vs 110 us for the register-shuffle S^T form and 240 us for
// the VGPR-clamped variant. Keep: K/V dbuf, one barrier per tile, XCD-local
// (b,h) in bid&63, ones-MFMA rowsum, exp2 with scale folded into Q, swizzled
// K/V staging. DO NOT add a second __launch_bounds__ arg (round-7 spill).
__global__ __launch_bounds__(256) void attn_fwd(ushort_t* __restrict__ QY,
                                                const ushort_t* __restrict__ K,
                                                const ushort_t* __restrict__ Vt) {
    __shared__ __align__(16) ushort_t Ks[2][64 * 64];    // [buf][kv][d], swizzled
    __shared__ __align__(16) ushort_t Vs[2][64 * 64];    // [buf][d][kv], swizzled
    __shared__ __align__(16) ushort_t Ps[4 * 32 * 72];   // per-wave [q=32][kv=64], stride 72
    const int tid = threadIdx.x;
    const int lane = tid & 63, wave = tid >> 6;
    const int lane15 = lane & 15, quad = lane >> 4;
    const int sw = lane15 & 7;                            // read-side swizzle key
    const int bid = blockIdx.x;
    const int hb = bid & 63, qslot = bid >> 6;
    const int qb = 15 - qslot;
    const int h = hb & 15, b = hb >> 4;
    const int q0 = qb * 128;
    const size_t baseR = (size_t)b * SEQ * CH + h * HSZ;      // +t*CH+d (Q,K,Y)
    const size_t baseV = ((size_t)b * 1024 + h * HSZ) * SEQ;  // +d*SEQ+t (Vt)
    const int rg = lane >> 3, cg = (lane & 7) ^ rg;           // staging swizzle

    short8 qf[2][2];
    #pragma unroll
    for (int mm = 0; mm < 2; mm++) {
        const ushort_t* qp = QY + baseR + (size_t)(q0 + wave * 32 + mm * 16 + lane15) * CH + quad * 8;
        qf[mm][0] = *(const short8*)qp;
        qf[mm][1] = *(const short8*)(qp + 32);
    }
    const short8 kOnes = (short8)(short)0x3F80;  // bf16 1.0 x8

    floatx4 o[2][5];  // [mm][0..3]=O d-chunks, [4]=l (rowsum)
    #pragma unroll
    for (int mm = 0; mm < 2; mm++)
        #pragma unroll
        for (int j = 0; j < 5; j++) o[mm][j] = {0.f, 0.f, 0.f, 0.f};

    const int nkt = 2 * qb + 2;
    // preamble: stage tile 0 into buf 0
    #pragma unroll
    for (int l = wave; l < 8; l += 4) {
        GLD16(K  + baseR + (size_t)(l * 8 + rg) * CH + cg * 8, &Ks[0][l * 512]);
        GLD16(Vt + baseV + (size_t)(l * 8 + rg) * SEQ + cg * 8, &Vs[0][l * 512]);
    }

    for (int kt = 0; kt < nkt; kt++) {
        __syncthreads();  // staging of kt landed; all waves done with buf kt^1
        const int cur = kt & 1;
        if (kt + 1 < nkt) {
            const int kv1 = (kt + 1) * 64, nb = cur ^ 1;
            #pragma unroll
            for (int l = wave; l < 8; l += 4) {
                GLD16(K  + baseR + (size_t)(kv1 + l * 8 + rg) * CH + cg * 8, &Ks[nb][l * 512]);
                GLD16(Vt + baseV + (size_t)(l * 8 + rg) * SEQ + kv1 + cg * 8, &Vs[nb][l * 512]);
            }
        }
        const int kv0 = kt * 64;
        const int masked = (kt >= 2 * qb);
        #pragma unroll
        for (int mm = 0; mm < 2; mm++) {
            floatx4 s4[4];
            #pragma unroll
            for (int j = 0; j < 4; j++) {
                short8 b0 = *(const short8*)&Ks[cur][(j * 16 + lane15) * 64 + ((quad ^ sw) * 8)];
                short8 b1 = *(const short8*)&Ks[cur][(j * 16 + lane15) * 64 + (((quad + 4) ^ sw) * 8)];
                floatx4 z = {0.f, 0.f, 0.f, 0.f};
                z = __builtin_amdgcn_mfma_f32_16x16x32_bf16(qf[mm][0], b0, z, 0, 0, 0);
                z = __builtin_amdgcn_mfma_f32_16x16x32_bf16(qf[mm][1], b1, z, 0, 0, 0);
                s4[j] = z;
            }
            const int qrow_base = q0 + wave * 32 + mm * 16 + quad * 4;
            if (masked) {
                #pragma unroll
                for (int j = 0; j < 4; j++) {
                    const int col = kv0 + j * 16 + lane15;
                    #pragma unroll
                    for (int r = 0; r < 4; r++)
                        s4[j][r] = (col <= qrow_base + r) ? s4[j][r] : -1e30f;
                }
            }
            // p = 2^s  (2^-1e30 -> 0 for masked lanes)
            #pragma unroll
            for (int j = 0; j < 4; j++)
                #pragma unroll
                for (int r = 0; r < 4; r++)
                    Ps[wave * 2304 + (mm * 16 + quad * 4 + r) * 72 + j * 16 + lane15] =
                        f2b(exp2f(s4[j][r]));
        }
        // Ps wave-private: lgkmcnt auto-wait orders write->read, no barrier

        #pragma unroll
        for (int kk = 0; kk < 2; kk++) {
            #pragma unroll
            for (int mm = 0; mm < 2; mm++) {
                short8 a = *(const short8*)&Ps[wave * 2304 + (mm * 16 + lane15) * 72 + kk * 32 + quad * 8];
                #pragma unroll
                for (int jn = 0; jn < 4; jn++) {
                    short8 bb = *(const short8*)&Vs[cur][(jn * 16 + lane15) * 64 + (((kk * 4 + quad) ^ sw) * 8)];
                    o[mm][jn] = __builtin_amdgcn_mfma_f32_16x16x32_bf16(a, bb, o[mm][jn], 0, 0, 0);
                }
                o[mm][4] = __builtin_amdgcn_mfma_f32_16x16x32_bf16(a, kOnes, o[mm][4], 0, 0, 0);
            }
        }
    }

    // epilogue: Y = O / l
    #pragma unroll
    for (int mm = 0; mm < 2; mm++)
        #pragma unroll
        for (int r = 0; r < 4; r++) {
            const int qrow = q0 + wave * 32 + mm * 16 + quad * 4 + r;
            const float rinv = 1.0f / fmaxf(o[mm][4][r], 1e-30f);
            #pragma unroll
            for (int jn = 0; jn < 4; jn++)
                QY[baseR + (size_t)qrow * CH + jn * 16 + lane15] = f2b(o[mm][jn][r] * rinv);
        }
}

extern "C" void kernel_launch(void* const* d_in, const int* in_sizes, int n_in,
                              void* d_out, int out_size, void* d_ws, size_t ws_size,
                              hipStream_t stream) {
    const void* x  = d_in[0];
    const void* Wk = d_in[1];
    const void* bk = d_in[2];
    const void* Wq = d_in[3];
    const void* bq = d_in[4];
    const void* Wv = d_in[5];
    const void* bv = d_in[6];
    const void* Wo = d_in[7];
    const void* bo = d_in[8];

    ushort_t* ws    = (ushort_t*)d_ws;
    int*      flag  = (int*)d_ws;
    ushort_t* biasC = ws + 2048;                    // 4x1024: q,k,v,o (contiguous)
    ushort_t* WqkvT = ws + 32768;                   // 3x1M contiguous: q,k,v
    ushort_t* WoT   = WqkvT + 3u * (1u << 20);
    ushort_t* xb    = ws + 4227072;                 // 8M elems bf16
    ushort_t* Qb    = ws + 12615680;                // 8M elems (becomes Y)
    ushort_t* Kb    = (ushort_t*)d_out;             // d_out scratch until final GEMM
    ushort_t* VtB   = Kb + (size_t)MROWS * CH;

    detect_dtype<<<1, 64, 0, stream>>>((const ushort_t*)x, flag);

    dim3 tgrid(32, 32, 4);
    convert_wt4<<<tgrid, 256, 0, stream>>>(Wq, Wk, Wv, Wo,
                                           WqkvT, WqkvT + (1u << 20), WqkvT + 2u * (1u << 20), WoT, flag);
    convert_bias4<<<16, 256, 0, stream>>>(bq, bk, bv, bo, biasC, flag);
    convert_x<<<MROWS * CH / (256 * 8), 256, 0, stream>>>(x, xb, flag);

    // scale = (1/sqrt(64)) * log2(e), folded into Q so attention uses exp2
    dim3 qgrid(MROWS / 128, 3 * CH / 128);
    gemm_qkv<<<qgrid, 256, 0, stream>>>(xb, WqkvT, biasC, Qb, Kb, VtB, 0.1803368801f);

    attn_fwd<<<dim3(1024), 256, 0, stream>>>(Qb, Kb, VtB);

    dim3 ogrid(MROWS / 128, CH / 128);
    gemm_bt<<<ogrid, 256, 0, stream>>>(Qb, WoT, biasC + 3072, d_out, MROWS, CH, CH, flag);
}